// Round 13
// baseline (164.587 us; speedup 1.0000x reference)
//
#include <hip/hip_runtime.h>
#include <stdint.h>

typedef __bf16 bf16x8 __attribute__((ext_vector_type(8)));
typedef float f32x4 __attribute__((ext_vector_type(4)));
typedef unsigned short u16x8 __attribute__((ext_vector_type(8)));

__device__ __forceinline__ unsigned short f2bf(float f) {
  uint32_t u = __builtin_bit_cast(uint32_t, f);
  u += 0x7FFFu + ((u >> 16) & 1u);   // RNE
  return (unsigned short)(u >> 16);
}
__device__ __forceinline__ float bf2f(unsigned short h) {
  uint32_t u = ((uint32_t)h) << 16;
  return __builtin_bit_cast(float, u);
}

__device__ __forceinline__ void gload_lds16(const void* g, void* l) {
  __builtin_amdgcn_global_load_lds(
      (const __attribute__((address_space(1))) uint32_t*)g,
      (__attribute__((address_space(3))) uint32_t*)l,
      16, 0, 0);
}

// ---------------- weight transpose kernel (x-convert now fused into GEMM1) --
// blocks [0,768): Wqkv [512][1536] -> wqT [1536][512] bf16
// blocks [768,1024): Wout [512][512] -> woT [512][512] bf16
__global__ __launch_bounds__(256) void k_cvt_w(
    const float* __restrict__ Wqkv, const float* __restrict__ Wout,
    unsigned short* __restrict__ wqT, unsigned short* __restrict__ woT) {
  int b = blockIdx.x;
  if (b < 768) {
    int stride = 768 * 256;
    for (int i = b * 256 + threadIdx.x; i < 786432; i += stride) {
      int n = i >> 9;                 // / 512
      int k = i & 511;
      wqT[i] = f2bf(Wqkv[(size_t)k * 1536 + n]);
    }
  } else {
    int stride = 256 * 256;
    for (int i = (b - 768) * 256 + threadIdx.x; i < 262144; i += stride) {
      int n = i >> 9;
      int k = i & 511;
      woT[i] = f2bf(Wout[(size_t)k * 512 + n]);
    }
  }
}

// ---- GEMM1 fused-cvt: C[M,1536] = bf16(X_f32[M,512]) * wqT[1536,512]^T ----
// 256x128 tile, BK=32, 8 waves (4Mx2N), wave-tile 64x64 (r11 geometry).
// A staged as RAW F32 via global_load_lds directly from x (cvt_x pass
// eliminated); converted to bf16 at LDS->reg time with native (__bf16)
// casts (RNE — numerically identical to the old cvt_x path).
// LDS: 2 bufs x (A-f32 32KB + B-bf16 8KB) = 80KB -> 2 blocks/CU =
// 16 waves/CU (same occupancy as r11's 71us kernel).
// Schedule: stage(kt+1) issued BEFORE compute(kt); tile-end vmcnt(0)+barrier.
// A swizzle (8 f32-chunks/row): source pre-swizzled s^(row&7), ds_read
// applies same involution (rule #21); uniform 8 lanes/bank-quad on b128.
// B swizzle unchanged (4 chunks/row, s^((row>>1)&3)).
// Epilogue: qkv scatter via LDS-bounce (proven r11 path).
__global__ __launch_bounds__(512, 4) void k_g1f(
    const float* __restrict__ X,
    const unsigned short* __restrict__ Bt,
    const float* __restrict__ bias,
    const float* __restrict__ brw,
    unsigned short* __restrict__ oq,
    unsigned short* __restrict__ okk,
    unsigned short* __restrict__ ov,
    int Ntiles) {
  __shared__ __align__(128) char lds[81920];  // buf b at b*40K: A 32KB + B 8KB

  int cpx = gridDim.x >> 3;
  int bid = (blockIdx.x & 7) * cpx + (blockIdx.x >> 3);
  int bm = bid / Ntiles;
  int bn = bid - bm * Ntiles;
  int row0 = bm << 8;
  int col0 = bn << 7;
  int t = threadIdx.x;
  int lane = t & 63;
  int w = t >> 6;        // wave 0..7
  int wm = w >> 1;       // 0..3  (M quadrant)
  int wn = w & 1;        // 0..1  (N half)
  int lr = lane & 15;
  int lk = lane >> 4;    // k-chunk 0..3 (8 bf16 each)

  const float* Xb = X + (size_t)row0 * 512;
  const unsigned short* Bb = Bt + (size_t)col0 * 512;

  f32x4 acc[4][4];
#pragma unroll
  for (int i = 0; i < 4; ++i)
#pragma unroll
    for (int j = 0; j < 4; ++j) acc[i][j] = f32x4{0.f, 0.f, 0.f, 0.f};

  // stage K-tile kt into buffer kt&1: A 4 gloads (f32) + B 1 gload (bf16)
  auto stage = [&](int kt) {
    char* base = lds + ((kt & 1) ? 40960 : 0);
    int k0 = kt << 5;                 // f32 element offset
#pragma unroll
    for (int i = 0; i < 4; ++i) {
      int o = (i << 9) + t;           // A chunk 0..2047 (256 rows x 8 chunks)
      int row = o >> 3;
      int s = o & 7;
      gload_lds16(Xb + (size_t)row * 512 + k0 + ((s ^ (row & 7)) << 2),
                  base + (o << 4));
    }
    {
      int o = t;                      // B chunk 0..511 (128 rows x 4 chunks)
      int row = o >> 2;
      int s = o & 3;
      gload_lds16(Bb + (size_t)row * 512 + (kt << 5) + ((s ^ ((row >> 1) & 3)) << 3),
                  base + 32768 + (o << 4));
    }
  };

  // compute K-tile in buffer kt&1: B 4 ds_read + A 8 f32-ds_read + cvt + 16 MFMA
  auto tile = [&](int kt) {
    const char* base = lds + ((kt & 1) ? 40960 : 0);
    const char* Bbuf = base + 32768;
    bf16x8 af[4], bfs[4];
#pragma unroll
    for (int nf = 0; nf < 4; ++nf) {
      int r = (wn << 6) + (nf << 4) + lr;
      bfs[nf] = *reinterpret_cast<const bf16x8*>(Bbuf + (r << 6) + ((lk ^ ((r >> 1) & 3)) << 4));
    }
#pragma unroll
    for (int mf = 0; mf < 4; ++mf) {
      int r = (wm << 6) + (mf << 4) + lr;
      int c0 = (lk << 1);
      f32x4 lo = *reinterpret_cast<const f32x4*>(base + (r << 7) + ((c0 ^ (r & 7)) << 4));
      f32x4 hi = *reinterpret_cast<const f32x4*>(base + (r << 7) + (((c0 + 1) ^ (r & 7)) << 4));
      bf16x8 a;
#pragma unroll
      for (int e = 0; e < 4; ++e) {
        a[e] = (__bf16)lo[e];
        a[4 + e] = (__bf16)hi[e];
      }
      af[mf] = a;
    }
    __builtin_amdgcn_s_setprio(1);
#pragma unroll
    for (int mf = 0; mf < 4; ++mf)
#pragma unroll
      for (int nf = 0; nf < 4; ++nf)
        acc[mf][nf] = __builtin_amdgcn_mfma_f32_16x16x32_bf16(af[mf], bfs[nf], acc[mf][nf], 0, 0, 0);
    __builtin_amdgcn_s_setprio(0);
  };

  // prologue
  stage(0);
  asm volatile("s_waitcnt vmcnt(0)" ::: "memory");
  __builtin_amdgcn_s_barrier();

#pragma unroll 1
  for (int kt = 0; kt < 15; ++kt) {
    stage(kt + 1);                 // 5 gloads to other buffer, in flight
    tile(kt);                      // 12 ds_read + cvt + 16 MFMA overlap them
    asm volatile("s_waitcnt vmcnt(0)" ::: "memory");
    __builtin_amdgcn_s_barrier();  // next tile ready; this buf's reads consumed
  }
  tile(15);
  __builtin_amdgcn_s_barrier();    // all reads done before LDS reuse

  // ---- epilogue: LDS-bounce (8KB/wave) then coalesced 16B stores ----
  char* ep = lds + (w << 13);      // 8 waves x 8KB = 64KB <= 80KB
  int gc0 = col0 + (wn << 6);
  int part = gc0 >> 9;             // 0=q 1=k 2=v (uniform per wave)
  int hh = (gc0 & 511) >> 6;
  unsigned short* dst = (part == 0) ? oq : (part == 1) ? okk : ov;
  float bvv[4], rbv[4];
#pragma unroll
  for (int nf = 0; nf < 4; ++nf) {
    int cc = (nf << 4) + lr;
    bvv[nf] = bias[gc0 + cc];
    rbv[nf] = (part == 0) ? brw[(gc0 & 511) + cc] : 0.f;
  }
#pragma unroll
  for (int mf = 0; mf < 4; ++mf) {
#pragma unroll
    for (int nf = 0; nf < 4; ++nf) {
      int cc = (nf << 4) + lr;
#pragma unroll
      for (int j = 0; j < 4; ++j) {
        int r = (mf << 4) + (lk << 2) + j;   // 0..63 within wave rows
        float v = acc[mf][nf][j] + bvv[nf];
        if (part == 0) v = v * 0.125f + rbv[nf];
        int byte = (r << 7) + ((((cc >> 3) ^ (r & 7))) << 4) + ((cc & 7) << 1);
        *reinterpret_cast<unsigned short*>(ep + byte) = f2bf(v);
      }
    }
  }
  asm volatile("s_waitcnt lgkmcnt(0)" ::: "memory");
  __builtin_amdgcn_sched_barrier(0);
  int b0 = row0 >> 11;
  size_t base = (size_t)(b0 * 8 + hh) * 2048;
#pragma unroll
  for (int i = 0; i < 8; ++i) {
    int rr = (i << 3) + (lane >> 3);
    int ch = lane & 7;
    int byte = (rr << 7) + ((ch ^ (rr & 7)) << 4);
    u16x8 val = *reinterpret_cast<const u16x8*>(ep + byte);
    int gl = (row0 + (wm << 6) + rr) & 2047;
    *reinterpret_cast<u16x8*>(dst + ((base + gl) << 6) + (ch << 3)) = val;
  }
}

// ---- GEMM2: 256x128, BK=32, triple-buffered, counted-vmcnt (r11 proven) ----
__global__ __launch_bounds__(512, 4) void k_gemm2(
    const unsigned short* __restrict__ A,
    const unsigned short* __restrict__ Bt,
    const float* __restrict__ bias,
    float* __restrict__ of,
    int Ntiles) {
  __shared__ __align__(128) char lds[73728];  // buf b at b*24K: A 16KB + B 8KB

  int cpx = gridDim.x >> 3;
  int bid = (blockIdx.x & 7) * cpx + (blockIdx.x >> 3);
  int bm = bid / Ntiles;
  int bn = bid - bm * Ntiles;
  int row0 = bm << 8;
  int col0 = bn << 7;
  int t = threadIdx.x;
  int lane = t & 63;
  int w = t >> 6;
  int wm = w >> 1;
  int wn = w & 1;
  int lr = lane & 15;
  int lk = lane >> 4;

  const unsigned short* Ab = A + (size_t)row0 * 512;
  const unsigned short* Bb = Bt + (size_t)col0 * 512;

  f32x4 acc[4][4];
#pragma unroll
  for (int i = 0; i < 4; ++i)
#pragma unroll
    for (int j = 0; j < 4; ++j) acc[i][j] = f32x4{0.f, 0.f, 0.f, 0.f};

  auto stage = [&](int kt, int b) {
    int k0 = kt << 5;
    char* base = lds + b * 24576;
#pragma unroll
    for (int i = 0; i < 2; ++i) {
      int o = (i << 9) + t;
      int row = o >> 2;
      int slot = o & 3;
      int gk = k0 + ((slot ^ ((row >> 1) & 3)) << 3);
      gload_lds16(Ab + (size_t)row * 512 + gk, base + (o << 4));
    }
    {
      int o = t;
      int row = o >> 2;
      int slot = o & 3;
      int gk = k0 + ((slot ^ ((row >> 1) & 3)) << 3);
      gload_lds16(Bb + (size_t)row * 512 + gk, base + 16384 + (o << 4));
    }
  };

  auto tile = [&](int b, int ktpf, int bpf, bool pf) {
    const char* Abuf = lds + b * 24576;
    const char* Bbuf = Abuf + 16384;
    bf16x8 af[4], bfs[4];
#pragma unroll
    for (int nf = 0; nf < 4; ++nf) {
      int r = (wn << 6) + (nf << 4) + lr;
      bfs[nf] = *reinterpret_cast<const bf16x8*>(Bbuf + (r << 6) + ((lk ^ ((r >> 1) & 3)) << 4));
    }
#pragma unroll
    for (int mf = 0; mf < 4; ++mf) {
      int r = (wm << 6) + (mf << 4) + lr;
      af[mf] = *reinterpret_cast<const bf16x8*>(Abuf + (r << 6) + ((lk ^ ((r >> 1) & 3)) << 4));
    }
    if (pf) stage(ktpf, bpf);
    __builtin_amdgcn_s_setprio(1);
#pragma unroll
    for (int mf = 0; mf < 4; ++mf)
#pragma unroll
      for (int nf = 0; nf < 4; ++nf)
        acc[mf][nf] = __builtin_amdgcn_mfma_f32_16x16x32_bf16(af[mf], bfs[nf], acc[mf][nf], 0, 0, 0);
    __builtin_amdgcn_s_setprio(0);
  };

  stage(0, 0);
  stage(1, 1);
  asm volatile("s_waitcnt vmcnt(3)" ::: "memory");
  __builtin_amdgcn_s_barrier();

  int cb = 0;
#pragma unroll 1
  for (int kt = 0; kt < 14; ++kt) {
    int pb = cb + 2; if (pb >= 3) pb -= 3;
    tile(cb, kt + 2, pb, true);
    asm volatile("s_waitcnt vmcnt(3)" ::: "memory");
    __builtin_amdgcn_s_barrier();
    ++cb; if (cb >= 3) cb -= 3;
  }
  tile(cb, 0, 0, false);               // kt = 14
  asm volatile("s_waitcnt vmcnt(0)" ::: "memory");
  __builtin_amdgcn_s_barrier();
  ++cb; if (cb >= 3) cb -= 3;
  tile(cb, 0, 0, false);               // kt = 15

#pragma unroll
  for (int mf = 0; mf < 4; ++mf) {
#pragma unroll
    for (int j = 0; j < 4; ++j) {
      int gr = row0 + (wm << 6) + (mf << 4) + (lk << 2) + j;
#pragma unroll
      for (int nf = 0; nf < 4; ++nf) {
        int gc = col0 + (wn << 6) + (nf << 4) + lr;
        of[(size_t)gr * 512 + gc] = acc[mf][nf][j] + bias[gc];
      }
    }
  }
}

// ---------------- banded attention, MFMA version ----------------
// q/k/v: [B*H][2048][64] bf16.  z: [32768][512] bf16 (col = h*64+e).
__global__ __launch_bounds__(256) void k_attn_mfma(
    const unsigned short* __restrict__ qb,
    const unsigned short* __restrict__ kb,
    const unsigned short* __restrict__ vb,
    unsigned short* __restrict__ zb) {
  __shared__ __align__(128) unsigned short smem[13312];  // Vt[0,6656) P[6656,13312)

  int t = threadIdx.x;
  int bh = blockIdx.x >> 5;
  int l0 = (blockIdx.x & 31) << 6;
  size_t slab = (size_t)bh << 17;

#pragma unroll
  for (int i = 0; i < 3; ++i) {
    int kloc = (i << 5) + (t >> 3);
    int c8 = (t & 7) << 3;
    int kg = l0 - 10 + kloc;
    kg = kg < 0 ? 0 : (kg > 2047 ? 2047 : kg);
    u16x8 v = *reinterpret_cast<const u16x8*>(vb + slab + ((size_t)kg << 6) + c8);
#pragma unroll
    for (int e = 0; e < 8; ++e) smem[(c8 + e) * 104 + kloc] = v[e];
  }

  int lane = t & 63;
  int w = t >> 6;
  int lr = lane & 15;
  int lk = lane >> 4;

  const unsigned short* qp = qb + slab + ((size_t)(l0 + (w << 4) + lr) << 6) + (lk << 3);
  bf16x8 qf0 = *reinterpret_cast<const bf16x8*>(qp);
  bf16x8 qf1 = *reinterpret_cast<const bf16x8*>(qp + 32);

  f32x4 sacc[6];
#pragma unroll
  for (int kt = 0; kt < 6; ++kt) {
    int kl = (kt << 4) + lr;
    int kg = l0 - 10 + kl;
    int kgc = kg < 0 ? 0 : (kg > 2047 ? 2047 : kg);
    const unsigned short* kp = kb + slab + ((size_t)kgc << 6) + (lk << 3);
    bf16x8 kf0 = *reinterpret_cast<const bf16x8*>(kp);
    bf16x8 kf1 = *reinterpret_cast<const bf16x8*>(kp + 32);
    f32x4 z4 = {0.f, 0.f, 0.f, 0.f};
    z4 = __builtin_amdgcn_mfma_f32_16x16x32_bf16(qf0, kf0, z4, 0, 0, 0);
    sacc[kt] = __builtin_amdgcn_mfma_f32_16x16x32_bf16(qf1, kf1, z4, 0, 0, 0);
  }

  int qlb = (w << 4) + (lk << 2);
  float p[6][4];
  float minv[4];
#pragma unroll
  for (int j = 0; j < 4; ++j) {
    int ql = qlb + j;
    float mx = -1e30f;
#pragma unroll
    for (int kt = 0; kt < 6; ++kt) {
      int kl = (kt << 4) + lr;
      int kg = l0 - 10 + kl;
      bool valid = (kl >= ql) && (kl <= ql + 20) && (kg >= 0) && (kg < 2048);
      float sv = valid ? sacc[kt][j] : -1e30f;
      p[kt][j] = sv;
      mx = fmaxf(mx, sv);
    }
    mx = fmaxf(mx, __shfl_xor(mx, 1));
    mx = fmaxf(mx, __shfl_xor(mx, 2));
    mx = fmaxf(mx, __shfl_xor(mx, 4));
    mx = fmaxf(mx, __shfl_xor(mx, 8));
    float sum = 0.f;
#pragma unroll
    for (int kt = 0; kt < 6; ++kt) {
      float e = (p[kt][j] > -1e29f) ? __expf(p[kt][j] - mx) : 0.f;
      p[kt][j] = e;
      sum += e;
    }
    sum += __shfl_xor(sum, 1);
    sum += __shfl_xor(sum, 2);
    sum += __shfl_xor(sum, 4);
    sum += __shfl_xor(sum, 8);
    minv[j] = 1.f / sum;
  }

  unsigned short* P = smem + 6656;
#pragma unroll
  for (int j = 0; j < 4; ++j)
#pragma unroll
    for (int kt = 0; kt < 6; ++kt)
      P[(qlb + j) * 104 + (kt << 4) + lr] = f2bf(p[kt][j]);

  __syncthreads();

  f32x4 zacc[4];
#pragma unroll
  for (int dt = 0; dt < 4; ++dt) zacc[dt] = f32x4{0.f, 0.f, 0.f, 0.f};
  bf16x8 pf[3];
#pragma unroll
  for (int s3 = 0; s3 < 3; ++s3)
    pf[s3] = *reinterpret_cast<const bf16x8*>(P + ((w << 4) + lr) * 104 + (s3 << 5) + (lk << 3));
#pragma unroll
  for (int dt = 0; dt < 4; ++dt) {
#pragma unroll
    for (int s3 = 0; s3 < 3; ++s3) {
      bf16x8 vf = *reinterpret_cast<const bf16x8*>(smem + ((dt << 4) + lr) * 104 + (s3 << 5) + (lk << 3));
      zacc[dt] = __builtin_amdgcn_mfma_f32_16x16x32_bf16(pf[s3], vf, zacc[dt], 0, 0, 0);
    }
  }

  __syncthreads();

  unsigned short* ZL = smem;
#pragma unroll
  for (int dt = 0; dt < 4; ++dt)
#pragma unroll
    for (int j = 0; j < 4; ++j)
      ZL[(qlb + j) * 80 + (dt << 4) + lr] = f2bf(zacc[dt][j] * minv[j]);
  asm volatile("s_waitcnt lgkmcnt(0)" ::: "memory");
  __builtin_amdgcn_sched_barrier(0);

  int b = bh >> 3, h = bh & 7;
#pragma unroll
  for (int i = 0; i < 2; ++i) {
    int rr = (w << 4) + (i << 3) + (lane >> 3);
    int ch = (lane & 7) << 3;
    u16x8 val = *reinterpret_cast<const u16x8*>(ZL + rr * 80 + ch);
    size_t orow = (size_t)(b * 2048 + l0 + rr);
    *reinterpret_cast<u16x8*>(zb + (orow << 9) + (h << 6) + ch) = val;
  }
}

// ---------------- launch ----------------

extern "C" void kernel_launch(void* const* d_in, const int* in_sizes, int n_in,
                              void* d_out, int out_size, void* d_ws, size_t ws_size,
                              hipStream_t stream) {
  (void)in_sizes; (void)n_in; (void)out_size; (void)ws_size;
  const float* x    = (const float*)d_in[0];
  const float* Wqkv = (const float*)d_in[1];
  const float* bqkv = (const float*)d_in[2];
  const float* brw  = (const float*)d_in[3];
  const float* Wout = (const float*)d_in[4];
  const float* bout = (const float*)d_in[5];
  float* out = (float*)d_out;

  char* ws = (char*)d_ws;
  unsigned short* zb  = (unsigned short*)(ws);               // z [32768][512] bf16
  unsigned short* wqT = (unsigned short*)(ws + 33554432);
  unsigned short* woT = (unsigned short*)(ws + 35127296);
  unsigned short* qs  = (unsigned short*)(ws + 35651584);
  unsigned short* kbf = (unsigned short*)(ws + 69206016);
  unsigned short* vbf = (unsigned short*)(ws + 102760448);

  k_cvt_w<<<1024, 256, 0, stream>>>(Wqkv, Wout, wqT, woT);
  k_g1f<<<1536, 512, 0, stream>>>(x, wqT, bqkv, brw, qs, kbf, vbf, 12);
  k_attn_mfma<<<4096, 256, 0, stream>>>(qs, kbf, vbf, zb);
  k_gemm2<<<512, 512, 0, stream>>>(zb, woT, bout, out, 4);
}

// Round 14
// 148.332 us; speedup vs baseline: 1.1096x; 1.1096x over previous
//
#include <hip/hip_runtime.h>
#include <stdint.h>

typedef __bf16 bf16x8 __attribute__((ext_vector_type(8)));
typedef float f32x4 __attribute__((ext_vector_type(4)));
typedef unsigned short u16x8 __attribute__((ext_vector_type(8)));

__device__ __forceinline__ unsigned short f2bf(float f) {
  uint32_t u = __builtin_bit_cast(uint32_t, f);
  u += 0x7FFFu + ((u >> 16) & 1u);   // RNE
  return (unsigned short)(u >> 16);
}
__device__ __forceinline__ float bf2f(unsigned short h) {
  uint32_t u = ((uint32_t)h) << 16;
  return __builtin_bit_cast(float, u);
}

__device__ __forceinline__ void gload_lds16(const void* g, void* l) {
  __builtin_amdgcn_global_load_lds(
      (const __attribute__((address_space(1))) uint32_t*)g,
      (__attribute__((address_space(3))) uint32_t*)l,
      16, 0, 0);
}

// ---------------- fused convert kernel (one launch) ----------------
// blocks [0,2048): x f32 -> xb bf16 (float4-vectorized)
// blocks [2048,2816): Wqkv [512][1536] -> wqT [1536][512] bf16
// blocks [2816,3072): Wout [512][512] -> woT [512][512] bf16
// NOTE (r13 lesson): do NOT fuse the x-convert into GEMM1 — f32 A-tiles in
// LDS have a 128B row stride (full bank rotation) -> systematic ds_read
// conflicts (6.3M counted) + 2x LDS write traffic; costs ~44us inside the
// GEMM vs ~14us saved outside.
__global__ __launch_bounds__(256) void k_cvt_all(
    const float* __restrict__ x, const float* __restrict__ Wqkv,
    const float* __restrict__ Wout, unsigned short* __restrict__ xb,
    unsigned short* __restrict__ wqT, unsigned short* __restrict__ woT) {
  int b = blockIdx.x;
  if (b < 2048) {
    int stride = 2048 * 256;
    for (int i = b * 256 + threadIdx.x; i < 4194304; i += stride) {
      float4 v = reinterpret_cast<const float4*>(x)[i];
      ushort4 o;
      o.x = f2bf(v.x); o.y = f2bf(v.y); o.z = f2bf(v.z); o.w = f2bf(v.w);
      reinterpret_cast<ushort4*>(xb)[i] = o;
    }
  } else if (b < 2816) {
    int stride = 768 * 256;
    for (int i = (b - 2048) * 256 + threadIdx.x; i < 786432; i += stride) {
      int n = i >> 9;                 // / 512
      int k = i & 511;
      wqT[i] = f2bf(Wqkv[(size_t)k * 1536 + n]);
    }
  } else {
    int stride = 256 * 256;
    for (int i = (b - 2816) * 256 + threadIdx.x; i < 262144; i += stride) {
      int n = i >> 9;
      int k = i & 511;
      woT[i] = f2bf(Wout[(size_t)k * 512 + n]);
    }
  }
}

// ---- GEMM 256x128, BK=32, TRIPLE-buffered, counted-vmcnt (r11/r12 proven) --
// C[M,N] = A[M,512] * Bt[N,512]^T. 8 waves (4Mx2N), wave-tile 64x64.
// LDS: 3 bufs x 24KB (A 16KB + B 8KB) = 72KB -> 2 blocks/CU = 16 waves/CU.
// Stage tile kt+2 during kt; tile-end s_waitcnt vmcnt(3) (kt+1's 3 loads
// done; kt+2's 3 stay in flight across the barrier — never drains) + barrier.
// Chunk swizzle slot^=(row>>1)&3 on BOTH stage source and ds_read (rule #21).
// EPI==0: qkv epilogue (bf16 LDS-bounce scatter); EPI==1: f32 C + bias.
template <int EPI>
__global__ __launch_bounds__(512, 4) void k_gemm256x128(
    const unsigned short* __restrict__ A,
    const unsigned short* __restrict__ Bt,
    const float* __restrict__ bias,
    const float* __restrict__ brw,
    unsigned short* __restrict__ oq,
    unsigned short* __restrict__ okk,
    unsigned short* __restrict__ ov,
    float* __restrict__ of,
    int Ntiles) {
  __shared__ __align__(128) char lds[73728];  // buf b at b*24K: A 16KB + B 8KB

  int cpx = gridDim.x >> 3;
  int bid = (blockIdx.x & 7) * cpx + (blockIdx.x >> 3);
  int bm = bid / Ntiles;
  int bn = bid - bm * Ntiles;
  int row0 = bm << 8;
  int col0 = bn << 7;
  int t = threadIdx.x;
  int lane = t & 63;
  int w = t >> 6;        // wave 0..7
  int wm = w >> 1;       // 0..3  (M quadrant)
  int wn = w & 1;        // 0..1  (N half)
  int lr = lane & 15;
  int lk = lane >> 4;    // k-chunk 0..3

  const unsigned short* Ab = A + (size_t)row0 * 512;
  const unsigned short* Bb = Bt + (size_t)col0 * 512;

  f32x4 acc[4][4];
#pragma unroll
  for (int i = 0; i < 4; ++i)
#pragma unroll
    for (int j = 0; j < 4; ++j) acc[i][j] = f32x4{0.f, 0.f, 0.f, 0.f};

  // stage K-tile kt into buffer b: 3 gloads/thread (2 A + 1 B)
  auto stage = [&](int kt, int b) {
    int k0 = kt << 5;
    char* base = lds + b * 24576;
#pragma unroll
    for (int i = 0; i < 2; ++i) {     // A: 1024 chunks (256 rows x 4 slots)
      int o = (i << 9) + t;
      int row = o >> 2;               // 0..255
      int slot = o & 3;
      int gk = k0 + ((slot ^ ((row >> 1) & 3)) << 3);
      gload_lds16(Ab + (size_t)row * 512 + gk, base + (o << 4));
    }
    {                                  // B: 512 chunks (128 rows x 4 slots)
      int o = t;
      int row = o >> 2;                // 0..127
      int slot = o & 3;
      int gk = k0 + ((slot ^ ((row >> 1) & 3)) << 3);
      gload_lds16(Bb + (size_t)row * 512 + gk, base + 16384 + (o << 4));
    }
  };

  // compute K-tile in buffer b (8 ds_read_b128 + 16 MFMA), maybe stage kt+2
  auto tile = [&](int b, int ktpf, int bpf, bool pf) {
    const char* Abuf = lds + b * 24576;
    const char* Bbuf = Abuf + 16384;
    bf16x8 af[4], bfs[4];
#pragma unroll
    for (int nf = 0; nf < 4; ++nf) {
      int r = (wn << 6) + (nf << 4) + lr;
      bfs[nf] = *reinterpret_cast<const bf16x8*>(Bbuf + (r << 6) + ((lk ^ ((r >> 1) & 3)) << 4));
    }
#pragma unroll
    for (int mf = 0; mf < 4; ++mf) {
      int r = (wm << 6) + (mf << 4) + lr;
      af[mf] = *reinterpret_cast<const bf16x8*>(Abuf + (r << 6) + ((lk ^ ((r >> 1) & 3)) << 4));
    }
    if (pf) stage(ktpf, bpf);
    __builtin_amdgcn_s_setprio(1);
#pragma unroll
    for (int mf = 0; mf < 4; ++mf)
#pragma unroll
      for (int nf = 0; nf < 4; ++nf)
        acc[mf][nf] = __builtin_amdgcn_mfma_f32_16x16x32_bf16(af[mf], bfs[nf], acc[mf][nf], 0, 0, 0);
    __builtin_amdgcn_s_setprio(0);
  };

  // prologue: stage tiles 0,1; wait tile 0 (tile 1's 3 loads in flight)
  stage(0, 0);
  stage(1, 1);
  asm volatile("s_waitcnt vmcnt(3)" ::: "memory");
  __builtin_amdgcn_s_barrier();

  int cb = 0;
#pragma unroll 1
  for (int kt = 0; kt < 14; ++kt) {
    int pb = cb + 2; if (pb >= 3) pb -= 3;
    tile(cb, kt + 2, pb, true);
    // kt+1's 3 loads are oldest of 6 outstanding; kt+2 stays in flight
    asm volatile("s_waitcnt vmcnt(3)" ::: "memory");
    __builtin_amdgcn_s_barrier();
    ++cb; if (cb >= 3) cb -= 3;
  }
  tile(cb, 0, 0, false);               // kt = 14
  asm volatile("s_waitcnt vmcnt(0)" ::: "memory");
  __builtin_amdgcn_s_barrier();
  ++cb; if (cb >= 3) cb -= 3;
  tile(cb, 0, 0, false);               // kt = 15
  __builtin_amdgcn_s_barrier();        // all reads done before LDS reuse

  if (EPI == 0) {
    // ---- epilogue: LDS-bounce (8KB/wave) then coalesced 16B stores ----
    char* ep = lds + (w << 13);        // 8 waves x 8KB = 64KB <= 72KB
    int gc0 = col0 + (wn << 6);
    int part = gc0 >> 9;               // 0=q 1=k 2=v (uniform per wave)
    int hh = (gc0 & 511) >> 6;
    unsigned short* dst = (part == 0) ? oq : (part == 1) ? okk : ov;
    float bvv[4], rbv[4];
#pragma unroll
    for (int nf = 0; nf < 4; ++nf) {
      int cc = (nf << 4) + lr;
      bvv[nf] = bias[gc0 + cc];
      rbv[nf] = (part == 0) ? brw[(gc0 & 511) + cc] : 0.f;
    }
#pragma unroll
    for (int mf = 0; mf < 4; ++mf) {
#pragma unroll
      for (int nf = 0; nf < 4; ++nf) {
        int cc = (nf << 4) + lr;
#pragma unroll
        for (int j = 0; j < 4; ++j) {
          int r = (mf << 4) + (lk << 2) + j;   // 0..63 within wave rows
          float v = acc[mf][nf][j] + bvv[nf];
          if (part == 0) v = v * 0.125f + rbv[nf];
          int byte = (r << 7) + ((((cc >> 3) ^ (r & 7))) << 4) + ((cc & 7) << 1);
          *reinterpret_cast<unsigned short*>(ep + byte) = f2bf(v);
        }
      }
    }
    asm volatile("s_waitcnt lgkmcnt(0)" ::: "memory");
    __builtin_amdgcn_sched_barrier(0);
    int b0 = row0 >> 11;
    size_t base = (size_t)(b0 * 8 + hh) * 2048;
#pragma unroll
    for (int i = 0; i < 8; ++i) {
      int rr = (i << 3) + (lane >> 3);
      int ch = lane & 7;
      int byte = (rr << 7) + ((ch ^ (rr & 7)) << 4);
      u16x8 val = *reinterpret_cast<const u16x8*>(ep + byte);
      int gl = (row0 + (wm << 6) + rr) & 2047;
      *reinterpret_cast<u16x8*>(dst + ((base + gl) << 6) + (ch << 3)) = val;
    }
  } else {
    // ---- epilogue: f32 C + bias, direct stores ----
#pragma unroll
    for (int mf = 0; mf < 4; ++mf) {
#pragma unroll
      for (int j = 0; j < 4; ++j) {
        int gr = row0 + (wm << 6) + (mf << 4) + (lk << 2) + j;
#pragma unroll
        for (int nf = 0; nf < 4; ++nf) {
          int gc = col0 + (wn << 6) + (nf << 4) + lr;
          of[(size_t)gr * 512 + gc] = acc[mf][nf][j] + bias[gc];
        }
      }
    }
  }
}

// ---------------- banded attention, MFMA version ----------------
// q/k/v: [B*H][2048][64] bf16.  z: [32768][512] bf16 (col = h*64+e).
__global__ __launch_bounds__(256) void k_attn_mfma(
    const unsigned short* __restrict__ qb,
    const unsigned short* __restrict__ kb,
    const unsigned short* __restrict__ vb,
    unsigned short* __restrict__ zb) {
  __shared__ __align__(128) unsigned short smem[13312];  // Vt[0,6656) P[6656,13312)

  int t = threadIdx.x;
  int bh = blockIdx.x >> 5;
  int l0 = (blockIdx.x & 31) << 6;
  size_t slab = (size_t)bh << 17;

#pragma unroll
  for (int i = 0; i < 3; ++i) {
    int kloc = (i << 5) + (t >> 3);
    int c8 = (t & 7) << 3;
    int kg = l0 - 10 + kloc;
    kg = kg < 0 ? 0 : (kg > 2047 ? 2047 : kg);
    u16x8 v = *reinterpret_cast<const u16x8*>(vb + slab + ((size_t)kg << 6) + c8);
#pragma unroll
    for (int e = 0; e < 8; ++e) smem[(c8 + e) * 104 + kloc] = v[e];
  }

  int lane = t & 63;
  int w = t >> 6;
  int lr = lane & 15;
  int lk = lane >> 4;

  const unsigned short* qp = qb + slab + ((size_t)(l0 + (w << 4) + lr) << 6) + (lk << 3);
  bf16x8 qf0 = *reinterpret_cast<const bf16x8*>(qp);
  bf16x8 qf1 = *reinterpret_cast<const bf16x8*>(qp + 32);

  f32x4 sacc[6];
#pragma unroll
  for (int kt = 0; kt < 6; ++kt) {
    int kl = (kt << 4) + lr;
    int kg = l0 - 10 + kl;
    int kgc = kg < 0 ? 0 : (kg > 2047 ? 2047 : kg);
    const unsigned short* kp = kb + slab + ((size_t)kgc << 6) + (lk << 3);
    bf16x8 kf0 = *reinterpret_cast<const bf16x8*>(kp);
    bf16x8 kf1 = *reinterpret_cast<const bf16x8*>(kp + 32);
    f32x4 z4 = {0.f, 0.f, 0.f, 0.f};
    z4 = __builtin_amdgcn_mfma_f32_16x16x32_bf16(qf0, kf0, z4, 0, 0, 0);
    sacc[kt] = __builtin_amdgcn_mfma_f32_16x16x32_bf16(qf1, kf1, z4, 0, 0, 0);
  }

  int qlb = (w << 4) + (lk << 2);
  float p[6][4];
  float minv[4];
#pragma unroll
  for (int j = 0; j < 4; ++j) {
    int ql = qlb + j;
    float mx = -1e30f;
#pragma unroll
    for (int kt = 0; kt < 6; ++kt) {
      int kl = (kt << 4) + lr;
      int kg = l0 - 10 + kl;
      bool valid = (kl >= ql) && (kl <= ql + 20) && (kg >= 0) && (kg < 2048);
      float sv = valid ? sacc[kt][j] : -1e30f;
      p[kt][j] = sv;
      mx = fmaxf(mx, sv);
    }
    mx = fmaxf(mx, __shfl_xor(mx, 1));
    mx = fmaxf(mx, __shfl_xor(mx, 2));
    mx = fmaxf(mx, __shfl_xor(mx, 4));
    mx = fmaxf(mx, __shfl_xor(mx, 8));
    float sum = 0.f;
#pragma unroll
    for (int kt = 0; kt < 6; ++kt) {
      float e = (p[kt][j] > -1e29f) ? __expf(p[kt][j] - mx) : 0.f;
      p[kt][j] = e;
      sum += e;
    }
    sum += __shfl_xor(sum, 1);
    sum += __shfl_xor(sum, 2);
    sum += __shfl_xor(sum, 4);
    sum += __shfl_xor(sum, 8);
    minv[j] = 1.f / sum;
  }

  unsigned short* P = smem + 6656;
#pragma unroll
  for (int j = 0; j < 4; ++j)
#pragma unroll
    for (int kt = 0; kt < 6; ++kt)
      P[(qlb + j) * 104 + (kt << 4) + lr] = f2bf(p[kt][j]);

  __syncthreads();

  f32x4 zacc[4];
#pragma unroll
  for (int dt = 0; dt < 4; ++dt) zacc[dt] = f32x4{0.f, 0.f, 0.f, 0.f};
  bf16x8 pf[3];
#pragma unroll
  for (int s3 = 0; s3 < 3; ++s3)
    pf[s3] = *reinterpret_cast<const bf16x8*>(P + ((w << 4) + lr) * 104 + (s3 << 5) + (lk << 3));
#pragma unroll
  for (int dt = 0; dt < 4; ++dt) {
#pragma unroll
    for (int s3 = 0; s3 < 3; ++s3) {
      bf16x8 vf = *reinterpret_cast<const bf16x8*>(smem + ((dt << 4) + lr) * 104 + (s3 << 5) + (lk << 3));
      zacc[dt] = __builtin_amdgcn_mfma_f32_16x16x32_bf16(pf[s3], vf, zacc[dt], 0, 0, 0);
    }
  }

  __syncthreads();

  unsigned short* ZL = smem;
#pragma unroll
  for (int dt = 0; dt < 4; ++dt)
#pragma unroll
    for (int j = 0; j < 4; ++j)
      ZL[(qlb + j) * 80 + (dt << 4) + lr] = f2bf(zacc[dt][j] * minv[j]);
  asm volatile("s_waitcnt lgkmcnt(0)" ::: "memory");
  __builtin_amdgcn_sched_barrier(0);

  int b = bh >> 3, h = bh & 7;
#pragma unroll
  for (int i = 0; i < 2; ++i) {
    int rr = (w << 4) + (i << 3) + (lane >> 3);
    int ch = (lane & 7) << 3;
    u16x8 val = *reinterpret_cast<const u16x8*>(ZL + rr * 80 + ch);
    size_t orow = (size_t)(b * 2048 + l0 + rr);
    *reinterpret_cast<u16x8*>(zb + (orow << 9) + (h << 6) + ch) = val;
  }
}

// ---------------- launch ----------------

extern "C" void kernel_launch(void* const* d_in, const int* in_sizes, int n_in,
                              void* d_out, int out_size, void* d_ws, size_t ws_size,
                              hipStream_t stream) {
  (void)in_sizes; (void)n_in; (void)out_size; (void)ws_size;
  const float* x    = (const float*)d_in[0];
  const float* Wqkv = (const float*)d_in[1];
  const float* bqkv = (const float*)d_in[2];
  const float* brw  = (const float*)d_in[3];
  const float* Wout = (const float*)d_in[4];
  const float* bout = (const float*)d_in[5];
  float* out = (float*)d_out;

  char* ws = (char*)d_ws;
  unsigned short* xb  = (unsigned short*)(ws);
  unsigned short* wqT = (unsigned short*)(ws + 33554432);
  unsigned short* woT = (unsigned short*)(ws + 35127296);
  unsigned short* qs  = (unsigned short*)(ws + 35651584);
  unsigned short* kbf = (unsigned short*)(ws + 69206016);
  unsigned short* vbf = (unsigned short*)(ws + 102760448);
  unsigned short* zb  = xb;  // safe reuse: x_bf only needed by GEMM1

  k_cvt_all<<<3072, 256, 0, stream>>>(x, Wqkv, Wout, xb, wqT, woT);
  k_gemm256x128<0><<<1536, 512, 0, stream>>>(xb, wqT, bqkv, brw, qs, kbf, vbf, nullptr, 12);
  k_attn_mfma<<<4096, 256, 0, stream>>>(qs, kbf, vbf, zb);
  k_gemm256x128<1><<<512, 512, 0, stream>>>(zb, woT, bout, nullptr, nullptr, nullptr, nullptr, out, 4);
}